// Round 12
// baseline (155.111 us; speedup 1.0000x reference)
//
#include <hip/hip_runtime.h>

#define TPB 256
#define EPB 4             // elements per block, 64 lanes / element (full wave)
#define H1S 246           // padded row stride for h1 (245 used; holds 140-vec later)
#define ES  280           // per-element slot: x(256) then h[140]|t30[60]

// ---- d_ws float offsets ----
#define WQ1   0      // 65
#define WQ2   65     // 450
#define WR1Q  515    // 100
#define WR2Q  615    // 100
#define WCQ   715    // 64 (c1 @715, c2 @747)
#define WSB   779    // 474 folded BN
#define SMALL_N 1253
// A-weights, blocked-transposed: [35 float4-col-blocks][140 fused rows] float4
#define WQAT  1280   // 19600
// B-weights, blocked-transposed: [35 float2-col-blocks][60 fused rows] float2
#define WQBT  20880  // 4200

// sb sub-offsets (relative to WSB): [scale[C] | bias[C]] per layer
#define SB_P1 0
#define SB_P2 10
#define SB_R1 30
#define SB_R2 50
#define SB_A1 70
#define SB_B1 210
#define SB_C1 270
#define SB_A2 272
#define SB_B2 412
#define SB_C2 472

// ---------------- prep: quantize weights + fold BN into ws ----------------
#define GFOLD(bn, C, OFF)                                                     \
  if (tid < (C)) {                                                            \
    float gg = (bn)[tid], bb = (bn)[(C) + tid];                               \
    float mm = (bn)[2 * (C) + tid], vv = (bn)[3 * (C) + tid];                 \
    float sc = gg / sqrtf(vv + 1e-5f);                                        \
    sbp[(OFF) + tid] = sc;                                                    \
    sbp[(OFF) + (C) + tid] = bb - mm * sc;                                    \
  }

extern "C" __global__ __launch_bounds__(256)
void prep(const float* __restrict__ w1,  const float* __restrict__ bnp1,
          const float* __restrict__ w2,  const float* __restrict__ bnp2,
          const float* __restrict__ wr1, const float* __restrict__ bnr1,
          const float* __restrict__ wr2, const float* __restrict__ bnr2,
          const float* __restrict__ wa1, const float* __restrict__ bna1,
          const float* __restrict__ wb1, const float* __restrict__ bnb1,
          const float* __restrict__ wc1, const float* __restrict__ bnc1,
          const float* __restrict__ wa2, const float* __restrict__ bna2,
          const float* __restrict__ wb2, const float* __restrict__ bnb2,
          const float* __restrict__ wc2, const float* __restrict__ bnc2,
          float* __restrict__ ws)
{
  __shared__ float s_red[4];
  const int tid = threadIdx.x;
  const int b = blockIdx.x;

  if (b == 10) {  // fold all BN params
    float* sbp = ws + WSB;
    GFOLD(bnp1, 5, SB_P1)  GFOLD(bnp2, 10, SB_P2)
    GFOLD(bnr1, 10, SB_R1) GFOLD(bnr2, 10, SB_R2)
    GFOLD(bna1, 70, SB_A1) GFOLD(bnb1, 30, SB_B1) GFOLD(bnc1, 1, SB_C1)
    GFOLD(bna2, 70, SB_A2) GFOLD(bnb2, 30, SB_B2) GFOLD(bnc2, 1, SB_C2)
    return;
  }

  const float* src; int n; int mode; int rofs; float* dst = ws;
  int ofs = 0;
  switch (b) {
    case 0: src = w1;  ofs = WQ1;      n = 65;   mode = 0; rofs = 0;  break;
    case 1: src = w2;  ofs = WQ2;      n = 450;  mode = 0; rofs = 0;  break;
    case 2: src = wr1; ofs = WR1Q;     n = 100;  mode = 0; rofs = 0;  break;
    case 3: src = wr2; ofs = WR2Q;     n = 100;  mode = 0; rofs = 0;  break;
    case 4: src = wa1; ofs = WQAT;     n = 9800; mode = 1; rofs = 0;  break;
    case 5: src = wb1; ofs = WQBT;     n = 2100; mode = 2; rofs = 0;  break;
    case 6: src = wc1; ofs = WCQ;      n = 30;   mode = 0; rofs = 0;  break;
    case 7: src = wa2; ofs = WQAT;     n = 9800; mode = 1; rofs = 70; break;
    case 8: src = wb2; ofs = WQBT;     n = 2100; mode = 2; rofs = 30; break;
    default:src = wc2; ofs = WCQ + 32; n = 30;   mode = 0; rofs = 0;  break;
  }

  float m = 0.f;
  for (int i = tid; i < n; i += 256) m = fmaxf(m, fabsf(src[i]));
#pragma unroll
  for (int off = 32; off > 0; off >>= 1)
    m = fmaxf(m, __shfl_down(m, off, 64));
  if ((tid & 63) == 0) s_red[tid >> 6] = m;
  __syncthreads();
  m = fmaxf(fmaxf(s_red[0], s_red[1]), fmaxf(s_red[2], s_red[3]));

  float s = m / 127.0f;
  for (int i = tid; i < n; i += 256) {
    float w = src[i];
    float q = rintf(fminf(fmaxf(w / s, -127.f), 127.f)) * s;
    if (mode == 0) {
      dst[ofs + i] = q;
    } else if (mode == 1) {           // A: row r, col c -> [c/4][r] float4
      int r = i / 140 + rofs, c = i % 140;
      dst[ofs + ((c >> 2) * 140 + r) * 4 + (c & 3)] = q;
    } else {                          // B: row r, col c -> [c/2][r] float2
      int r = i / 70 + rofs, c = i % 70;
      dst[ofs + ((c >> 1) * 60 + r) * 2 + (c & 1)] = q;
    }
  }
}

// ---- main: 64 lanes/element (wave-private), ZERO barriers -----------------
// R12 = R6's 64-lane/element lane maps (leanest P1-P4 VALU; 8192 waves =
// 32/CU supply, LDS 13.4 KB -> 11 blk/CU so all resident) + R11's A/B
// (blocked-transposed coalesced weights, cb-outer single h-read) +
// (,4) bounds (VGPR ~48-64; R6 only failed because (,8) forced 32 + spill).
extern "C" __global__ __launch_bounds__(TPB, 4)
void taunet(const float* __restrict__ x, const float* __restrict__ ws,
            float* __restrict__ out, int B)
{
  __shared__ __align__(16) float s_h1[EPB * H1S];   // pre1 out; later 140-vec
  __shared__ __align__(16) float s_e[EPB * ES];     // x -> h[140]|t30[60]
  __shared__ __align__(16) float s_small[SMALL_N];

  const int tid = threadIdx.x;
  const int g  = tid >> 6;    // element within block == wave id
  const int l  = tid & 63;    // lane within element/wave
  const int elem = blockIdx.x * EPB + g;

  // per-wave redundant copy of small weights+BN (identical values -> benign
  // race; each wave's own writes are ordered before its reads => no barrier)
  for (int i = l; i < SMALL_N; i += 64) s_small[i] = ws[i];

  // stage x: each wave stages its own element (64 x float4, coalesced)
  if (elem < B) {
    float4 v = ((const float4*)x)[elem * 64 + l];
    *(float4*)&s_e[g * ES + l * 4] = v;
  }

  const float* sb = &s_small[WSB];

  // ---- P1: pre1 (Cin=1, K=13, stride 5) -> h1[5][49], single pass ----
  // weights + BN wave-uniform from ws[] -> scalar s_loads (SMEM pipe)
  {
    const float* xe = &s_e[g * ES];
    bool act = l < 49;
    int ps = act ? l : 0;
    float win[13];
#pragma unroll
    for (int k = 0; k < 13; ++k) win[k] = xe[5 * ps + k];
#pragma unroll
    for (int ci = 0; ci < 5; ++ci) {
      float a0 = 0.f, a1 = 0.f;
#pragma unroll
      for (int k = 0; k < 13; ++k) {
        float d = fabsf(win[k] - ws[WQ1 + ci * 13 + k]);
        if (k & 1) a1 += d; else a0 += d;
      }
      float v = fmaxf(fmaf(-(a0 + a1), ws[WSB + SB_P1 + ci],
                           ws[WSB + SB_P1 + 5 + ci]), 0.f);
      if (act) s_h1[g * H1S + ci * 49 + ps] = v;
    }
  }

  // ---- P2: pre2 (Cin=5, K=9, stride 3) -> h2[10][14] ----
  // lane = ow(14 of 16) x co-group(4): groups {0-2, 3-5, 6-7, 8-9}
  {
    const int ch = l >> 4;                 // 0..3
    const int ow16 = l & 15;
    const bool act = ow16 < 14;
    const int ow = act ? ow16 : 0;
    const int base = ch * 3 - (ch == 3 ? 1 : 0);   // 0,3,6,8
    const int n = 3 - (ch >> 1);                   // 3,3,2,2
    const float* h1b = &s_h1[g * H1S];
    float acc[3] = {0.f, 0.f, 0.f};
#pragma unroll
    for (int ci = 0; ci < 5; ++ci) {
      float w9[9];
#pragma unroll
      for (int k = 0; k < 9; ++k) w9[k] = h1b[ci * 49 + 3 * ow + k];
#pragma unroll
      for (int c = 0; c < 3; ++c) {
        int co = base + c; co = co > 9 ? 9 : co;   // clamp (inactive c only)
        float s0 = 0.f, s1 = 0.f;
#pragma unroll
        for (int k = 0; k < 9; ++k) {
          float d = fabsf(w9[k] - s_small[WQ2 + co * 45 + ci * 9 + k]);
          if (k & 1) s1 += d; else s0 += d;
        }
        acc[c] += s0 + s1;
      }
    }
#pragma unroll
    for (int c = 0; c < 3; ++c) {
      if (act && c < n) {
        int co = base + c;
        float v = fmaxf(fmaf(-acc[c], sb[SB_P2 + co], sb[SB_P2 + 10 + co]), 0.f);
        s_e[g * ES + co * 14 + ow] = v;
      }
    }
  }

  // ---- P3: r1 (10x10, K=1) + relu -> t1 ----
#pragma unroll
  for (int j = 0; j < 3; ++j) {
    int idx = l + 64 * j;
    if (idx < 140) {
      int co = idx / 14, ow = idx % 14;
      float a0 = 0.f, a1 = 0.f;
#pragma unroll
      for (int ci = 0; ci < 10; ++ci) {
        float d = fabsf(s_e[g * ES + ci * 14 + ow] - s_small[WR1Q + co * 10 + ci]);
        if (ci & 1) a1 += d; else a0 += d;
      }
      s_e[g * ES + 140 + idx] =
          fmaxf(fmaf(-(a0 + a1), sb[SB_R1 + co], sb[SB_R1 + 10 + co]), 0.f);
    }
  }

  // ---- P4: r2 (no relu) + residual, h = relu(t2 + h2), in place ----
#pragma unroll
  for (int j = 0; j < 3; ++j) {
    int idx = l + 64 * j;
    if (idx < 140) {
      int co = idx / 14, ow = idx % 14;
      float a0 = 0.f, a1 = 0.f;
#pragma unroll
      for (int ci = 0; ci < 10; ++ci) {
        float d = fabsf(s_e[g * ES + 140 + ci * 14 + ow] - s_small[WR2Q + co * 10 + ci]);
        if (ci & 1) a1 += d; else a0 += d;
      }
      float t2 = fmaf(-(a0 + a1), sb[SB_R2 + co], sb[SB_R2 + 10 + co]);
      s_e[g * ES + idx] = fmaxf(t2 + s_e[g * ES + idx], 0.f);
    }
  }

  // ---- A/B fused branches (ws layout: WQA2/WQB2 contiguous after 1) ----
  {
    const float* hb = &s_e[g * ES];

    // A: cb-outer; h4 LDS-read ONCE per cb (35 b128/wave); 3 row-sets in
    // 12 acc regs; dense float4 weight loads. unroll 2 (spill discipline).
    const int r2 = (l + 128 > 139) ? 139 : l + 128;
    const int rows[3] = {l, l + 64, r2};
    float accA[3][4];
#pragma unroll
    for (int p = 0; p < 3; ++p)
#pragma unroll
      for (int j = 0; j < 4; ++j) accA[p][j] = 0.f;
#pragma unroll 2
    for (int cb = 0; cb < 35; ++cb) {
      float4 h4 = *(const float4*)&hb[cb * 4];
#pragma unroll
      for (int p = 0; p < 3; ++p) {
        float4 w4 = *(const float4*)&ws[WQAT + (cb * 140 + rows[p]) * 4];
        accA[p][0] += fabsf(h4.x - w4.x);
        accA[p][1] += fabsf(h4.y - w4.y);
        accA[p][2] += fabsf(h4.z - w4.z);
        accA[p][3] += fabsf(h4.w - w4.w);
      }
    }
#pragma unroll
    for (int p = 0; p < 3; ++p) {
      int cl = rows[p];
      bool act = (p < 2) || (l < 12);
      if (act) {
        int co  = cl < 70 ? cl : cl - 70;
        int off = cl < 70 ? SB_A1 : SB_A2;
        float sc = sb[off + co], bi = sb[off + 70 + co];
        float sad = (accA[p][0] + accA[p][1]) + (accA[p][2] + accA[p][3]);
        s_h1[g * H1S + cl] = fmaxf(fmaf(-sad, sc, bi), 0.f);
      }
    }

    // B: 60 fused rows (30/branch) one pass; dense float2 weight loads
    {
      bool act = l < 60;
      int rl = act ? l : 0;
      int br = rl >= 30;
      int co = br ? rl - 30 : rl;
      const float* h70 = &s_h1[g * H1S + br * 70];
      int off = br ? SB_B2 : SB_B1;
      float a0 = 0.f, a1 = 0.f;
#pragma unroll 8
      for (int ci = 0; ci < 35; ++ci) {
        float2 w2v = *(const float2*)&ws[WQBT + (ci * 60 + rl) * 2];
        a0 += fabsf(h70[2 * ci]     - w2v.x);
        a1 += fabsf(h70[2 * ci + 1] - w2v.y);
      }
      if (act)
        s_e[g * ES + 140 + rl] =
            fmaxf(fmaf(-(a0 + a1), sb[off + co], sb[off + 30 + co]), 0.f);
    }

    // C: both branches at once; half-wave width-32 trees (bit-identical to
    // R5's per-branch width-32 reduction). lane 0 -> br0, lane 32 -> br1.
    {
      int hw = l >> 5;          // 0 = branch0 half, 1 = branch1 half
      int i  = l & 31;
      float d = 0.f;
      if (i < 30)
        d = fabsf(s_e[g * ES + 140 + hw * 30 + i] - s_small[WCQ + hw * 32 + i]);
#pragma unroll
      for (int off = 16; off > 0; off >>= 1)
        d += __shfl_down(d, off, 32);
      if (i == 0 && elem < B) {
        int sbC = hw ? SB_C2 : SB_C1;
        out[hw * B + elem] = fmaxf(fmaf(-d, sb[sbC], sb[sbC + 1]), 0.f);
      }
    }
  }
}

extern "C" void kernel_launch(void* const* d_in, const int* in_sizes, int n_in,
                              void* d_out, int out_size, void* d_ws, size_t ws_size,
                              hipStream_t stream) {
  const float* x    = (const float*)d_in[0];
  const float* w1   = (const float*)d_in[1];
  const float* bnp1 = (const float*)d_in[2];
  const float* w2   = (const float*)d_in[3];
  const float* bnp2 = (const float*)d_in[4];
  const float* wr1  = (const float*)d_in[5];
  const float* bnr1 = (const float*)d_in[6];
  const float* wr2  = (const float*)d_in[7];
  const float* bnr2 = (const float*)d_in[8];
  const float* wa1  = (const float*)d_in[9];
  const float* bna1 = (const float*)d_in[10];
  const float* wb1  = (const float*)d_in[11];
  const float* bnb1 = (const float*)d_in[12];
  const float* wc1  = (const float*)d_in[13];
  const float* bnc1 = (const float*)d_in[14];
  const float* wa2  = (const float*)d_in[15];
  const float* bna2 = (const float*)d_in[16];
  const float* wb2  = (const float*)d_in[17];
  const float* bnb2 = (const float*)d_in[18];
  const float* wc2  = (const float*)d_in[19];
  const float* bnc2 = (const float*)d_in[20];

  float* ws = (float*)d_ws;
  int B = in_sizes[0] / 256;
  int blocks = (B + EPB - 1) / EPB;

  hipLaunchKernelGGL(prep, dim3(11), dim3(256), 0, stream,
                     w1, bnp1, w2, bnp2, wr1, bnr1, wr2, bnr2,
                     wa1, bna1, wb1, bnb1, wc1, bnc1,
                     wa2, bna2, wb2, bnb2, wc2, bnc2, ws);

  hipLaunchKernelGGL(taunet, dim3(blocks), dim3(TPB), 0, stream,
                     x, ws, (float*)d_out, B);
}

// Round 13
// 148.395 us; speedup vs baseline: 1.0453x; 1.0453x over previous
//
#include <hip/hip_runtime.h>

#define TPB 256
#define EPB 16            // elements per block; each wave owns 4 elements
#define H1S 246           // padded row stride for h1 (245 used; holds 140-vec later)
#define ES  280           // per-element slot: x(256) then h[140]|t30[60]

// ---- d_ws float offsets ----
#define WQ1   0      // 65
#define WQ2   65     // 450
#define WR1Q  515    // 100
#define WR2Q  615    // 100
#define WCQ   715    // 64 (c1 @715, c2 @747)
#define WSB   779    // 474 folded BN
#define SMALL_N 1253
// A-weights, blocked-transposed: [35 float4-col-blocks][140 fused rows] float4
#define WQAT  1280   // 19600
// B-weights, blocked-transposed: [35 float2-col-blocks][60 fused rows] float2
#define WQBT  20880  // 4200

// sb sub-offsets (relative to WSB): [scale[C] | bias[C]] per layer
#define SB_P1 0
#define SB_P2 10
#define SB_R1 30
#define SB_R2 50
#define SB_A1 70
#define SB_B1 210
#define SB_C1 270
#define SB_A2 272
#define SB_B2 412
#define SB_C2 472

// ---------------- prep: quantize weights + fold BN into ws ----------------
#define GFOLD(bn, C, OFF)                                                     \
  if (tid < (C)) {                                                            \
    float gg = (bn)[tid], bb = (bn)[(C) + tid];                               \
    float mm = (bn)[2 * (C) + tid], vv = (bn)[3 * (C) + tid];                 \
    float sc = gg / sqrtf(vv + 1e-5f);                                        \
    sbp[(OFF) + tid] = sc;                                                    \
    sbp[(OFF) + (C) + tid] = bb - mm * sc;                                    \
  }

extern "C" __global__ __launch_bounds__(256)
void prep(const float* __restrict__ w1,  const float* __restrict__ bnp1,
          const float* __restrict__ w2,  const float* __restrict__ bnp2,
          const float* __restrict__ wr1, const float* __restrict__ bnr1,
          const float* __restrict__ wr2, const float* __restrict__ bnr2,
          const float* __restrict__ wa1, const float* __restrict__ bna1,
          const float* __restrict__ wb1, const float* __restrict__ bnb1,
          const float* __restrict__ wc1, const float* __restrict__ bnc1,
          const float* __restrict__ wa2, const float* __restrict__ bna2,
          const float* __restrict__ wb2, const float* __restrict__ bnb2,
          const float* __restrict__ wc2, const float* __restrict__ bnc2,
          float* __restrict__ ws)
{
  __shared__ float s_red[4];
  const int tid = threadIdx.x;
  const int b = blockIdx.x;

  if (b == 10) {  // fold all BN params
    float* sbp = ws + WSB;
    GFOLD(bnp1, 5, SB_P1)  GFOLD(bnp2, 10, SB_P2)
    GFOLD(bnr1, 10, SB_R1) GFOLD(bnr2, 10, SB_R2)
    GFOLD(bna1, 70, SB_A1) GFOLD(bnb1, 30, SB_B1) GFOLD(bnc1, 1, SB_C1)
    GFOLD(bna2, 70, SB_A2) GFOLD(bnb2, 30, SB_B2) GFOLD(bnc2, 1, SB_C2)
    return;
  }

  const float* src; int n; int mode; int rofs; float* dst = ws;
  int ofs = 0;
  switch (b) {
    case 0: src = w1;  ofs = WQ1;      n = 65;   mode = 0; rofs = 0;  break;
    case 1: src = w2;  ofs = WQ2;      n = 450;  mode = 0; rofs = 0;  break;
    case 2: src = wr1; ofs = WR1Q;     n = 100;  mode = 0; rofs = 0;  break;
    case 3: src = wr2; ofs = WR2Q;     n = 100;  mode = 0; rofs = 0;  break;
    case 4: src = wa1; ofs = WQAT;     n = 9800; mode = 1; rofs = 0;  break;
    case 5: src = wb1; ofs = WQBT;     n = 2100; mode = 2; rofs = 0;  break;
    case 6: src = wc1; ofs = WCQ;      n = 30;   mode = 0; rofs = 0;  break;
    case 7: src = wa2; ofs = WQAT;     n = 9800; mode = 1; rofs = 70; break;
    case 8: src = wb2; ofs = WQBT;     n = 2100; mode = 2; rofs = 30; break;
    default:src = wc2; ofs = WCQ + 32; n = 30;   mode = 0; rofs = 0;  break;
  }

  float m = 0.f;
  for (int i = tid; i < n; i += 256) m = fmaxf(m, fabsf(src[i]));
#pragma unroll
  for (int off = 32; off > 0; off >>= 1)
    m = fmaxf(m, __shfl_down(m, off, 64));
  if ((tid & 63) == 0) s_red[tid >> 6] = m;
  __syncthreads();
  m = fmaxf(fmaxf(s_red[0], s_red[1]), fmaxf(s_red[2], s_red[3]));

  float s = m / 127.0f;
  for (int i = tid; i < n; i += 256) {
    float w = src[i];
    float q = rintf(fminf(fmaxf(w / s, -127.f), 127.f)) * s;
    if (mode == 0) {
      dst[ofs + i] = q;
    } else if (mode == 1) {           // A: row r, col c -> [c/4][r] float4
      int r = i / 140 + rofs, c = i % 140;
      dst[ofs + ((c >> 2) * 140 + r) * 4 + (c & 3)] = q;
    } else {                          // B: row r, col c -> [c/2][r] float2
      int r = i / 70 + rofs, c = i % 70;
      dst[ofs + ((c >> 1) * 60 + r) * 2 + (c & 1)] = q;
    }
  }
}

// ---- main: wave owns 4 elements, ZERO barriers ----------------------------
// Cost model (R10-R12 post-mortems): weight amortization/elem >> LDS instrs
// >> VALU. This config: A/B weight loads shared x4; P2-P4 lane=(elem,ow)
// (56/64 active) makes co-loops wave-uniform -> P2/P3/P4 weights via SCALAR
// s_loads and h2/t1 in registers (zero LDS). ~150 LDS instr/elem vs R11 ~380.
extern "C" __global__ __launch_bounds__(TPB, 4)
void taunet(const float* __restrict__ x, const float* __restrict__ ws,
            float* __restrict__ out, int B)
{
  __shared__ __align__(16) float s_h1[EPB * H1S];   // pre1 out; later 140-vec
  __shared__ __align__(16) float s_e[EPB * ES];     // x -> h[140]|t30[60]
  __shared__ __align__(16) float s_small[SMALL_N];  // only [WCQ..) staged

  const int tid = threadIdx.x;
  const int l  = tid & 63;    // lane within wave
  const int wv = tid >> 6;    // wave within block
  const int gp = 4 * wv;      // wave's first element slot (owns gp..gp+3)
  const int ebase = blockIdx.x * EPB + gp;

  // stage lane-varying constants (A/B sb lookups, C weights)
  for (int i = WCQ + l; i < SMALL_N; i += 64) s_small[i] = ws[i];

  // stage x: wave stages its 4 elements (coalesced float4)
  {
    const float4* xb = (const float4*)x;
#pragma unroll
    for (int j = 0; j < 4; ++j) {
      int ge = ebase + j;
      if (ge < B) {
        float4 v = xb[ge * 64 + l];
        *(float4*)&s_e[(gp + j) * ES + l * 4] = v;
      }
    }
  }

  // ---- P1: pre1 (Cin=1, K=13, stride 5) -> h1[5][49]; one pass/element ----
  // weights + BN wave-uniform from ws[] -> scalar s_loads (SMEM pipe)
#pragma unroll
  for (int j = 0; j < 4; ++j) {
    const float* xe = &s_e[(gp + j) * ES];
    bool act = l < 49;
    int ps = act ? l : 0;
    float win[13];
#pragma unroll
    for (int k = 0; k < 13; ++k) win[k] = xe[5 * ps + k];
#pragma unroll
    for (int ci = 0; ci < 5; ++ci) {
      float a0 = 0.f, a1 = 0.f;
#pragma unroll
      for (int k = 0; k < 13; ++k) {
        float d = fabsf(win[k] - ws[WQ1 + ci * 13 + k]);
        if (k & 1) a1 += d; else a0 += d;
      }
      float v = fmaxf(fmaf(-(a0 + a1), ws[WSB + SB_P1 + ci],
                           ws[WSB + SB_P1 + 5 + ci]), 0.f);
      if (act) s_h1[(gp + j) * H1S + ci * 49 + ps] = v;
    }
  }

  // ---- P2-P4 lane map: lane = elem(l>>4) x ow(l&15, 14 active) ----------
  const int eloc = l >> 4;            // 0..3: which of the wave's elements
  const int slot = gp + eloc;         // element slot in LDS
  const int ow16 = l & 15;
  const bool act = ow16 < 14;
  const int ow = act ? ow16 : 0;

  // ---- P2: pre2 (Cin=5, K=9, stride 3); co wave-uniform -> scalar w ----
  float h2r[10];
  {
    const float* h1b = &s_h1[slot * H1S];
    float acc[10] = {0.f,0.f,0.f,0.f,0.f,0.f,0.f,0.f,0.f,0.f};
#pragma unroll
    for (int ci = 0; ci < 5; ++ci) {
      float w9[9];
#pragma unroll
      for (int k = 0; k < 9; ++k) w9[k] = h1b[ci * 49 + 3 * ow + k];
#pragma unroll
      for (int co = 0; co < 10; ++co) {
        float s0 = 0.f, s1 = 0.f;
#pragma unroll
        for (int k = 0; k < 9; ++k) {
          float d = fabsf(w9[k] - ws[WQ2 + co * 45 + ci * 9 + k]);
          if (k & 1) s1 += d; else s0 += d;
        }
        acc[co] += s0 + s1;
      }
    }
#pragma unroll
    for (int co = 0; co < 10; ++co)
      h2r[co] = fmaxf(fmaf(-acc[co], ws[WSB + SB_P2 + co],
                           ws[WSB + SB_P2 + 10 + co]), 0.f);
  }

  // ---- P3: r1 + relu, registers only ----
  float t1r[10];
#pragma unroll
  for (int co = 0; co < 10; ++co) {
    float a0 = 0.f, a1 = 0.f;
#pragma unroll
    for (int ci = 0; ci < 10; ++ci) {
      float d = fabsf(h2r[ci] - ws[WR1Q + co * 10 + ci]);
      if (ci & 1) a1 += d; else a0 += d;
    }
    t1r[co] = fmaxf(fmaf(-(a0 + a1), ws[WSB + SB_R1 + co],
                         ws[WSB + SB_R1 + 10 + co]), 0.f);
  }

  // ---- P4: r2 + residual; h = relu(t2 + h2) -> LDS (A-phase needs it) ----
#pragma unroll
  for (int co = 0; co < 10; ++co) {
    float a0 = 0.f, a1 = 0.f;
#pragma unroll
    for (int ci = 0; ci < 10; ++ci) {
      float d = fabsf(t1r[ci] - ws[WR2Q + co * 10 + ci]);
      if (ci & 1) a1 += d; else a0 += d;
    }
    float t2 = fmaf(-(a0 + a1), ws[WSB + SB_R2 + co], ws[WSB + SB_R2 + 10 + co]);
    float h = fmaxf(t2 + h2r[co], 0.f);
    if (act) s_e[slot * ES + co * 14 + ow] = h;
  }

  // ---- A: 140 fused rows; cb-outer; weights shared by 4 elements --------
  {
    const int r2 = (l + 128 > 139) ? 139 : l + 128;
    const int rows[3] = {l, l + 64, r2};
    float acc[3][4][4];   // [row-set][element][component]
#pragma unroll
    for (int p = 0; p < 3; ++p)
#pragma unroll
      for (int e = 0; e < 4; ++e)
#pragma unroll
        for (int c = 0; c < 4; ++c) acc[p][e][c] = 0.f;
#pragma unroll 1
    for (int cb = 0; cb < 35; ++cb) {
      float4 h4[4];
#pragma unroll
      for (int e = 0; e < 4; ++e)
        h4[e] = *(const float4*)&s_e[(gp + e) * ES + cb * 4];
#pragma unroll
      for (int p = 0; p < 3; ++p) {
        float4 w4 = *(const float4*)&ws[WQAT + (cb * 140 + rows[p]) * 4];
#pragma unroll
        for (int e = 0; e < 4; ++e) {
          acc[p][e][0] += fabsf(h4[e].x - w4.x);
          acc[p][e][1] += fabsf(h4[e].y - w4.y);
          acc[p][e][2] += fabsf(h4[e].z - w4.z);
          acc[p][e][3] += fabsf(h4[e].w - w4.w);
        }
      }
    }
#pragma unroll
    for (int p = 0; p < 3; ++p) {
      int cl = rows[p];
      bool pact = (p < 2) || (l < 12);
      if (pact) {
        int co  = cl < 70 ? cl : cl - 70;
        int off = cl < 70 ? SB_A1 : SB_A2;
        float sc = s_small[WSB + off + co], bi = s_small[WSB + off + 70 + co];
#pragma unroll
        for (int e = 0; e < 4; ++e) {
          float sad = (acc[p][e][0] + acc[p][e][1]) + (acc[p][e][2] + acc[p][e][3]);
          s_h1[(gp + e) * H1S + cl] = fmaxf(fmaf(-sad, sc, bi), 0.f);
        }
      }
    }
  }

  // ---- B: 60 fused rows; weights shared by 4 elements; float2 h reads ----
  {
    bool bact = l < 60;
    int rl = bact ? l : 0;
    int br = rl >= 30;
    int co = br ? rl - 30 : rl;
    int off = br ? SB_B2 : SB_B1;
    float a0[4], a1[4];
#pragma unroll
    for (int e = 0; e < 4; ++e) { a0[e] = 0.f; a1[e] = 0.f; }
#pragma unroll 4
    for (int ci = 0; ci < 35; ++ci) {
      float2 w2v = *(const float2*)&ws[WQBT + (ci * 60 + rl) * 2];
#pragma unroll
      for (int e = 0; e < 4; ++e) {
        float2 h2 = *(const float2*)&s_h1[(gp + e) * H1S + br * 70 + 2 * ci];
        a0[e] += fabsf(h2.x - w2v.x);
        a1[e] += fabsf(h2.y - w2v.y);
      }
    }
    if (bact) {
      float sc = s_small[WSB + off + co], bi = s_small[WSB + off + 30 + co];
#pragma unroll
      for (int e = 0; e < 4; ++e)
        s_e[(gp + e) * ES + 140 + rl] =
            fmaxf(fmaf(-(a0[e] + a1[e]), sc, bi), 0.f);
    }
  }

  // ---- C: per element, both branches via half-wave width-32 trees ----
#pragma unroll
  for (int j = 0; j < 4; ++j) {
    int hw = l >> 5;          // 0 = branch0 half, 1 = branch1 half
    int i  = l & 31;
    float d = 0.f;
    if (i < 30)
      d = fabsf(s_e[(gp + j) * ES + 140 + hw * 30 + i] -
                s_small[WCQ + hw * 32 + i]);
#pragma unroll
    for (int off = 16; off > 0; off >>= 1)
      d += __shfl_down(d, off, 32);
    if (i == 0 && (ebase + j) < B) {
      int sbC = hw ? SB_C2 : SB_C1;
      out[hw * B + (ebase + j)] =
          fmaxf(fmaf(-d, ws[WSB + sbC], ws[WSB + sbC + 1]), 0.f);
    }
  }
}

extern "C" void kernel_launch(void* const* d_in, const int* in_sizes, int n_in,
                              void* d_out, int out_size, void* d_ws, size_t ws_size,
                              hipStream_t stream) {
  const float* x    = (const float*)d_in[0];
  const float* w1   = (const float*)d_in[1];
  const float* bnp1 = (const float*)d_in[2];
  const float* w2   = (const float*)d_in[3];
  const float* bnp2 = (const float*)d_in[4];
  const float* wr1  = (const float*)d_in[5];
  const float* bnr1 = (const float*)d_in[6];
  const float* wr2  = (const float*)d_in[7];
  const float* bnr2 = (const float*)d_in[8];
  const float* wa1  = (const float*)d_in[9];
  const float* bna1 = (const float*)d_in[10];
  const float* wb1  = (const float*)d_in[11];
  const float* bnb1 = (const float*)d_in[12];
  const float* wc1  = (const float*)d_in[13];
  const float* bnc1 = (const float*)d_in[14];
  const float* wa2  = (const float*)d_in[15];
  const float* bna2 = (const float*)d_in[16];
  const float* wb2  = (const float*)d_in[17];
  const float* bnb2 = (const float*)d_in[18];
  const float* wc2  = (const float*)d_in[19];
  const float* bnc2 = (const float*)d_in[20];

  float* ws = (float*)d_ws;
  int B = in_sizes[0] / 256;
  int blocks = (B + EPB - 1) / EPB;

  hipLaunchKernelGGL(prep, dim3(11), dim3(256), 0, stream,
                     w1, bnp1, w2, bnp2, wr1, bnr1, wr2, bnr2,
                     wa1, bna1, wb1, bnb1, wc1, bnc1,
                     wa2, bna2, wb2, bnb2, wc2, bnc2, ws);

  hipLaunchKernelGGL(taunet, dim3(blocks), dim3(TPB), 0, stream,
                     x, ws, (float*)d_out, B);
}

// Round 14
// 141.986 us; speedup vs baseline: 1.0924x; 1.0451x over previous
//
#include <hip/hip_runtime.h>

#define TPB 256
#define EPB 8             // elements per block; wave owns 2 (half-wave each in P1-P4)
#define H1S 246           // padded row stride for h1 (245 used; holds 140-vec later)
#define ES  280           // per-element slot: x(256) then h[140]|t30[60]

// ---- d_ws float offsets ----
#define WQ1   0      // 65
#define WQ2   65     // 450 (legacy, unused)
#define WR1Q  515    // 100 (legacy, unused)
#define WR2Q  615    // 100 (legacy, unused)
#define WCQ   715    // 64 (c1 @715, c2 @747)
#define WSB   779    // 474 folded BN
#define SMALL_N 1253
// A-weights, blocked-transposed: [35 float4-col-blocks][140 fused rows] float4
#define WQAT  1280   // 19600
// B-weights, blocked-transposed: [35 float2-col-blocks][60 fused rows] float2
#define WQBT  20880  // 4200
// padded small weights (12-float rows -> 16B-aligned b128 LDS reads)
#define WQ2P  25080  // w2  as [10co][5ci][12] = 600
#define WR1P  25680  // wr1 as [10co][12] = 120
#define WR2P  25800  // wr2 as [10co][12] = 120  (ws end: 25920 floats)

// s_small local offsets for the padded regions (16B-aligned: 1256 % 4 == 0)
#define LP2   1256
#define LR1   1856
#define LR2   1976
#define SM_TOT 2096

// sb sub-offsets (relative to WSB): [scale[C] | bias[C]] per layer
#define SB_P1 0
#define SB_P2 10
#define SB_R1 30
#define SB_R2 50
#define SB_A1 70
#define SB_B1 210
#define SB_C1 270
#define SB_A2 272
#define SB_B2 412
#define SB_C2 472

// ---------------- prep: quantize weights + fold BN into ws ----------------
#define GFOLD(bn, C, OFF)                                                     \
  if (tid < (C)) {                                                            \
    float gg = (bn)[tid], bb = (bn)[(C) + tid];                               \
    float mm = (bn)[2 * (C) + tid], vv = (bn)[3 * (C) + tid];                 \
    float sc = gg / sqrtf(vv + 1e-5f);                                        \
    sbp[(OFF) + tid] = sc;                                                    \
    sbp[(OFF) + (C) + tid] = bb - mm * sc;                                    \
  }

extern "C" __global__ __launch_bounds__(256)
void prep(const float* __restrict__ w1,  const float* __restrict__ bnp1,
          const float* __restrict__ w2,  const float* __restrict__ bnp2,
          const float* __restrict__ wr1, const float* __restrict__ bnr1,
          const float* __restrict__ wr2, const float* __restrict__ bnr2,
          const float* __restrict__ wa1, const float* __restrict__ bna1,
          const float* __restrict__ wb1, const float* __restrict__ bnb1,
          const float* __restrict__ wc1, const float* __restrict__ bnc1,
          const float* __restrict__ wa2, const float* __restrict__ bna2,
          const float* __restrict__ wb2, const float* __restrict__ bnb2,
          const float* __restrict__ wc2, const float* __restrict__ bnc2,
          float* __restrict__ ws)
{
  __shared__ float s_red[4];
  const int tid = threadIdx.x;
  const int b = blockIdx.x;

  if (b == 10) {  // fold all BN params
    float* sbp = ws + WSB;
    GFOLD(bnp1, 5, SB_P1)  GFOLD(bnp2, 10, SB_P2)
    GFOLD(bnr1, 10, SB_R1) GFOLD(bnr2, 10, SB_R2)
    GFOLD(bna1, 70, SB_A1) GFOLD(bnb1, 30, SB_B1) GFOLD(bnc1, 1, SB_C1)
    GFOLD(bna2, 70, SB_A2) GFOLD(bnb2, 30, SB_B2) GFOLD(bnc2, 1, SB_C2)
    return;
  }

  const float* src; int n; int mode; int rofs; float* dst = ws;
  // mode 0: contiguous; 1: A-transpose; 2: B-transpose; 3: P2 pad-12; 4: R pad-12
  int ofs = 0;
  switch (b) {
    case 0: src = w1;  ofs = WQ1;      n = 65;   mode = 0; rofs = 0;  break;
    case 1: src = w2;  ofs = WQ2P;     n = 450;  mode = 3; rofs = 0;  break;
    case 2: src = wr1; ofs = WR1P;     n = 100;  mode = 4; rofs = 0;  break;
    case 3: src = wr2; ofs = WR2P;     n = 100;  mode = 4; rofs = 0;  break;
    case 4: src = wa1; ofs = WQAT;     n = 9800; mode = 1; rofs = 0;  break;
    case 5: src = wb1; ofs = WQBT;     n = 2100; mode = 2; rofs = 0;  break;
    case 6: src = wc1; ofs = WCQ;      n = 30;   mode = 0; rofs = 0;  break;
    case 7: src = wa2; ofs = WQAT;     n = 9800; mode = 1; rofs = 70; break;
    case 8: src = wb2; ofs = WQBT;     n = 2100; mode = 2; rofs = 30; break;
    default:src = wc2; ofs = WCQ + 32; n = 30;   mode = 0; rofs = 0;  break;
  }

  float m = 0.f;
  for (int i = tid; i < n; i += 256) m = fmaxf(m, fabsf(src[i]));
#pragma unroll
  for (int off = 32; off > 0; off >>= 1)
    m = fmaxf(m, __shfl_down(m, off, 64));
  if ((tid & 63) == 0) s_red[tid >> 6] = m;
  __syncthreads();
  m = fmaxf(fmaxf(s_red[0], s_red[1]), fmaxf(s_red[2], s_red[3]));

  float s = m / 127.0f;
  for (int i = tid; i < n; i += 256) {
    float w = src[i];
    float q = rintf(fminf(fmaxf(w / s, -127.f), 127.f)) * s;
    if (mode == 0) {
      dst[ofs + i] = q;
    } else if (mode == 1) {           // A: row r, col c -> [c/4][r] float4
      int r = i / 140 + rofs, c = i % 140;
      dst[ofs + ((c >> 2) * 140 + r) * 4 + (c & 3)] = q;
    } else if (mode == 2) {           // B: row r, col c -> [c/2][r] float2
      int r = i / 70 + rofs, c = i % 70;
      dst[ofs + ((c >> 1) * 60 + r) * 2 + (c & 1)] = q;
    } else if (mode == 3) {           // w2: (co,ci,k) -> co*60 + ci*12 + k
      int co = i / 45, rem = i % 45;
      dst[ofs + co * 60 + (rem / 9) * 12 + rem % 9] = q;
    } else {                          // wr: (co,ci) -> co*12 + ci
      dst[ofs + (i / 10) * 12 + i % 10] = q;
    }
  }
}

// -------- main pipeline: wave owns 2 elements, ZERO barriers --------------
// R14 = R11 + wide LDS weight reads: P2/P3/P4 weight rows padded to 12
// floats (16B-aligned) -> b128/b64 loads. LDS instr/wave ~712 -> ~490
// (P2 weights 225 b32 -> 75; P3/P4 weights 100 -> 30). Accumulation order
// preserved exactly (explicit even/odd unroll).
extern "C" __global__ __launch_bounds__(TPB, 4)
void taunet(const float* __restrict__ x, const float* __restrict__ ws,
            float* __restrict__ out, int B)
{
  __shared__ __align__(16) float s_h1[EPB * H1S];   // pre1 out; later 140-vec
  __shared__ __align__(16) float s_e[EPB * ES];     // x -> h[140]|t30[60]
  __shared__ __align__(16) float s_small[SM_TOT];

  const int tid = threadIdx.x;
  const int g  = tid >> 5;    // element slot within block (half-wave)
  const int l  = tid & 31;    // lane within element (P1-P4, C)
  const int ln = tid & 63;    // lane within wave
  const int wv = tid >> 6;    // wave within block
  const int gp = 2 * wv;      // wave's first element slot
  const int elem = blockIdx.x * EPB + g;

  // per-wave redundant copy of small weights+BN (identical values -> benign
  // race; each wave's own writes are ordered before its reads => no barrier)
  for (int i = ln; i < SMALL_N; i += 64) s_small[i] = ws[i];
  for (int i = ln; i < 840; i += 64) s_small[LP2 + i] = ws[WQ2P + i];

  // stage x: wave stages its own two elements (coalesced float4)
  {
    const float4* xb = (const float4*)x;
#pragma unroll
    for (int it = 0; it < 2; ++it) {
      int e = gp + it;
      int ge = blockIdx.x * EPB + e;
      if (ge < B) {
        float4 v = xb[ge * 64 + ln];
        *(float4*)&s_e[e * ES + ln * 4] = v;
      }
    }
  }

  const float* sb = &s_small[WSB];

  // ---- P1: pre1 (Cin=1, K=13, stride 5) -> h1[5][49] ----
  // weights + BN wave-uniform from ws[] -> scalar s_loads (SMEM pipe)
  {
    const float* xe = &s_e[g * ES];
#pragma unroll
    for (int rep = 0; rep < 2; ++rep) {
      int p = l + 32 * rep;
      bool act = p < 49;
      int ps = act ? p : 0;
      float win[13];
#pragma unroll
      for (int k = 0; k < 13; ++k) win[k] = xe[5 * ps + k];
#pragma unroll
      for (int ci = 0; ci < 5; ++ci) {
        float a0 = 0.f, a1 = 0.f;
#pragma unroll
        for (int k = 0; k < 13; ++k) {
          float d = fabsf(win[k] - ws[WQ1 + ci * 13 + k]);
          if (k & 1) a1 += d; else a0 += d;
        }
        float v = fmaxf(fmaf(-(a0 + a1), ws[WSB + SB_P1 + ci],
                             ws[WSB + SB_P1 + 5 + ci]), 0.f);
        if (act) s_h1[g * H1S + ci * 49 + ps] = v;
      }
    }
  }

  // ---- P2: pre2 (Cin=5, K=9, stride 3) -> h2[10][14] ----
  // half-wave: lane = ow(14 of 16) x co-half(2); ci-outer, 9-reg window;
  // weights via b128/b32 from padded [co][ci][12] (order = even/odd of R11)
  {
    const int ch = l >> 4;
    const int ow16 = l & 15;
    const bool act = ow16 < 14;
    const int ow = act ? ow16 : 0;
    const float* h1b = &s_h1[g * H1S];
    float acc[5] = {0.f, 0.f, 0.f, 0.f, 0.f};
#pragma unroll
    for (int ci = 0; ci < 5; ++ci) {
      float w9[9];
#pragma unroll
      for (int k = 0; k < 9; ++k) w9[k] = h1b[ci * 49 + 3 * ow + k];
#pragma unroll
      for (int c = 0; c < 5; ++c) {
        int co = ch * 5 + c;
        const float* wb = &s_small[LP2 + co * 60 + ci * 12];
        float4 wlo = *(const float4*)&wb[0];
        float4 whi = *(const float4*)&wb[4];
        float w8 = wb[8];
        float s0 = 0.f, s1 = 0.f;
        s0 += fabsf(w9[0] - wlo.x);
        s1 += fabsf(w9[1] - wlo.y);
        s0 += fabsf(w9[2] - wlo.z);
        s1 += fabsf(w9[3] - wlo.w);
        s0 += fabsf(w9[4] - whi.x);
        s1 += fabsf(w9[5] - whi.y);
        s0 += fabsf(w9[6] - whi.z);
        s1 += fabsf(w9[7] - whi.w);
        s0 += fabsf(w9[8] - w8);
        acc[c] += s0 + s1;
      }
    }
#pragma unroll
    for (int c = 0; c < 5; ++c) {
      int co = ch * 5 + c;
      float v = fmaxf(fmaf(-acc[c], sb[SB_P2 + co], sb[SB_P2 + 10 + co]), 0.f);
      if (act) s_e[g * ES + co * 14 + ow] = v;
    }
  }

  // ---- P3: r1 (10x10, K=1) + relu -> t1; weights b128x2+b64 padded ----
#pragma unroll
  for (int j = 0; j < 5; ++j) {
    int idx = l + 32 * j;
    if (idx < 140) {
      int co = idx / 14, ow = idx % 14;
      const float* wr = &s_small[LR1 + co * 12];
      float4 w0 = *(const float4*)&wr[0];
      float4 w1v = *(const float4*)&wr[4];
      float2 w2v = *(const float2*)&wr[8];
      const float* hbase = &s_e[g * ES + ow];
      float a0 = 0.f, a1 = 0.f;
      a0 += fabsf(hbase[0 * 14] - w0.x);
      a1 += fabsf(hbase[1 * 14] - w0.y);
      a0 += fabsf(hbase[2 * 14] - w0.z);
      a1 += fabsf(hbase[3 * 14] - w0.w);
      a0 += fabsf(hbase[4 * 14] - w1v.x);
      a1 += fabsf(hbase[5 * 14] - w1v.y);
      a0 += fabsf(hbase[6 * 14] - w1v.z);
      a1 += fabsf(hbase[7 * 14] - w1v.w);
      a0 += fabsf(hbase[8 * 14] - w2v.x);
      a1 += fabsf(hbase[9 * 14] - w2v.y);
      s_e[g * ES + 140 + idx] =
          fmaxf(fmaf(-(a0 + a1), sb[SB_R1 + co], sb[SB_R1 + 10 + co]), 0.f);
    }
  }

  // ---- P4: r2 (no relu) + residual, h = relu(t2 + h2), in place ----
#pragma unroll
  for (int j = 0; j < 5; ++j) {
    int idx = l + 32 * j;
    if (idx < 140) {
      int co = idx / 14, ow = idx % 14;
      const float* wr = &s_small[LR2 + co * 12];
      float4 w0 = *(const float4*)&wr[0];
      float4 w1v = *(const float4*)&wr[4];
      float2 w2v = *(const float2*)&wr[8];
      const float* tbase = &s_e[g * ES + 140 + ow];
      float a0 = 0.f, a1 = 0.f;
      a0 += fabsf(tbase[0 * 14] - w0.x);
      a1 += fabsf(tbase[1 * 14] - w0.y);
      a0 += fabsf(tbase[2 * 14] - w0.z);
      a1 += fabsf(tbase[3 * 14] - w0.w);
      a0 += fabsf(tbase[4 * 14] - w1v.x);
      a1 += fabsf(tbase[5 * 14] - w1v.y);
      a0 += fabsf(tbase[6 * 14] - w1v.z);
      a1 += fabsf(tbase[7 * 14] - w1v.w);
      a0 += fabsf(tbase[8 * 14] - w2v.x);
      a1 += fabsf(tbase[9 * 14] - w2v.y);
      float t2 = fmaf(-(a0 + a1), sb[SB_R2 + co], sb[SB_R2 + 10 + co]);
      s_e[g * ES + idx] = fmaxf(t2 + s_e[g * ES + idx], 0.f);
    }
  }

  // ---- A/B fused branches, wave-wide ----
  {
    const float* hb0 = &s_e[gp * ES];         // element e0 = gp
    const float* hb1 = &s_e[(gp + 1) * ES];   // element e1 = gp+1

    // A: cb-outer; h4/k4 LDS-read ONCE per cb (70 b128/wave vs 210);
    // 3 row-sets accumulate in 24 regs. unroll 2 (spill discipline).
    const int r2 = (ln + 128 > 139) ? 139 : ln + 128;
    const int rows[3] = {ln, ln + 64, r2};
    float accA[3][4], accB[3][4];
#pragma unroll
    for (int p = 0; p < 3; ++p)
#pragma unroll
      for (int j = 0; j < 4; ++j) { accA[p][j] = 0.f; accB[p][j] = 0.f; }
#pragma unroll 2
    for (int cb = 0; cb < 35; ++cb) {
      float4 h4 = *(const float4*)&hb0[cb * 4];
      float4 k4 = *(const float4*)&hb1[cb * 4];
#pragma unroll
      for (int p = 0; p < 3; ++p) {
        float4 w4 = *(const float4*)&ws[WQAT + (cb * 140 + rows[p]) * 4];
        accA[p][0] += fabsf(h4.x - w4.x);
        accA[p][1] += fabsf(h4.y - w4.y);
        accA[p][2] += fabsf(h4.z - w4.z);
        accA[p][3] += fabsf(h4.w - w4.w);
        accB[p][0] += fabsf(k4.x - w4.x);
        accB[p][1] += fabsf(k4.y - w4.y);
        accB[p][2] += fabsf(k4.z - w4.z);
        accB[p][3] += fabsf(k4.w - w4.w);
      }
    }
#pragma unroll
    for (int p = 0; p < 3; ++p) {
      int cl = rows[p];
      bool act = (p < 2) || (ln < 12);
      if (act) {
        int co  = cl < 70 ? cl : cl - 70;
        int off = cl < 70 ? SB_A1 : SB_A2;
        float sc = sb[off + co], bi = sb[off + 70 + co];
        float sadA = (accA[p][0] + accA[p][1]) + (accA[p][2] + accA[p][3]);
        float sadB = (accB[p][0] + accB[p][1]) + (accB[p][2] + accB[p][3]);
        s_h1[gp * H1S + cl]       = fmaxf(fmaf(-sadA, sc, bi), 0.f);
        s_h1[(gp + 1) * H1S + cl] = fmaxf(fmaf(-sadB, sc, bi), 0.f);
      }
    }

    // B: 60 fused rows in one pass; dense float2 weight loads
    {
      bool act = ln < 60;
      int rl = act ? ln : 0;
      int br = rl >= 30;
      int co = br ? rl - 30 : rl;
      const float* h0 = &s_h1[gp * H1S + br * 70];
      const float* h1 = &s_h1[(gp + 1) * H1S + br * 70];
      int off = br ? SB_B2 : SB_B1;
      float a0 = 0.f, a1 = 0.f, b0 = 0.f, b1 = 0.f;
#pragma unroll 8
      for (int ci = 0; ci < 35; ++ci) {
        float2 w2v = *(const float2*)&ws[WQBT + (ci * 60 + rl) * 2];
        a0 += fabsf(h0[2 * ci]     - w2v.x);
        a1 += fabsf(h0[2 * ci + 1] - w2v.y);
        b0 += fabsf(h1[2 * ci]     - w2v.x);
        b1 += fabsf(h1[2 * ci + 1] - w2v.y);
      }
      if (act) {
        float sc = sb[off + co], bi = sb[off + 30 + co];
        s_e[gp * ES + 140 + rl]       = fmaxf(fmaf(-(a0 + a1), sc, bi), 0.f);
        s_e[(gp + 1) * ES + 140 + rl] = fmaxf(fmaf(-(b0 + b1), sc, bi), 0.f);
      }
    }

    // C: per element (half-wave), both branches sequentially; width-32 tree
    for (int br = 0; br < 2; ++br) {
      float d = 0.f;
      if (l < 30)
        d = fabsf(s_e[g * ES + 140 + br * 30 + l] - s_small[WCQ + br * 32 + l]);
#pragma unroll
      for (int off = 16; off > 0; off >>= 1)
        d += __shfl_down(d, off, 32);
      if (l == 0 && elem < B) {
        int sbC = br ? SB_C2 : SB_C1;
        out[br * B + elem] = fmaxf(fmaf(-d, sb[sbC], sb[sbC + 1]), 0.f);
      }
    }
  }
}

extern "C" void kernel_launch(void* const* d_in, const int* in_sizes, int n_in,
                              void* d_out, int out_size, void* d_ws, size_t ws_size,
                              hipStream_t stream) {
  const float* x    = (const float*)d_in[0];
  const float* w1   = (const float*)d_in[1];
  const float* bnp1 = (const float*)d_in[2];
  const float* w2   = (const float*)d_in[3];
  const float* bnp2 = (const float*)d_in[4];
  const float* wr1  = (const float*)d_in[5];
  const float* bnr1 = (const float*)d_in[6];
  const float* wr2  = (const float*)d_in[7];
  const float* bnr2 = (const float*)d_in[8];
  const float* wa1  = (const float*)d_in[9];
  const float* bna1 = (const float*)d_in[10];
  const float* wb1  = (const float*)d_in[11];
  const float* bnb1 = (const float*)d_in[12];
  const float* wc1  = (const float*)d_in[13];
  const float* bnc1 = (const float*)d_in[14];
  const float* wa2  = (const float*)d_in[15];
  const float* bna2 = (const float*)d_in[16];
  const float* wb2  = (const float*)d_in[17];
  const float* bnb2 = (const float*)d_in[18];
  const float* wc2  = (const float*)d_in[19];
  const float* bnc2 = (const float*)d_in[20];

  float* ws = (float*)d_ws;
  int B = in_sizes[0] / 256;
  int blocks = (B + EPB - 1) / EPB;

  hipLaunchKernelGGL(prep, dim3(11), dim3(256), 0, stream,
                     w1, bnp1, w2, bnp2, wr1, bnr1, wr2, bnr2,
                     wa1, bna1, wb1, bnb1, wc1, bnc1,
                     wa2, bna2, wb2, bnb2, wc2, bnc2, ws);

  hipLaunchKernelGGL(taunet, dim3(blocks), dim3(TPB), 0, stream,
                     x, ws, (float*)d_out, B);
}

// Round 15
// 137.659 us; speedup vs baseline: 1.1268x; 1.0314x over previous
//
#include <hip/hip_runtime.h>

#define TPB 256
#define EPB 8             // elements per block; wave owns 2 (half-wave each in P1-P4)
#define H1S 246           // padded row stride for h1 (245 used; holds 140-vec later)
#define ES  280           // per-element slot: x(256) then h[140]|t30[60]

// ---- d_ws float offsets ----
#define WQ1   0      // 65
#define WQ2   65     // 450
#define WR1Q  515    // 100
#define WR2Q  615    // 100
#define WCQ   715    // 64 (c1 @715, c2 @747)
#define WSB   779    // 474 folded BN
#define SMALL_N 1253
// A-weights, blocked-transposed: [35 float4-col-blocks][140 fused rows] float4
#define WQAT  1280   // 19600
// B-weights, blocked-transposed: [35 float2-col-blocks][60 fused rows] float2
#define WQBT  20880  // 4200

// sb sub-offsets (relative to WSB): [scale[C] | bias[C]] per layer
#define SB_P1 0
#define SB_P2 10
#define SB_R1 30
#define SB_R2 50
#define SB_A1 70
#define SB_B1 210
#define SB_C1 270
#define SB_A2 272
#define SB_B2 412
#define SB_C2 472

// ---------------- prep: quantize weights + fold BN into ws ----------------
#define GFOLD(bn, C, OFF)                                                     \
  if (tid < (C)) {                                                            \
    float gg = (bn)[tid], bb = (bn)[(C) + tid];                               \
    float mm = (bn)[2 * (C) + tid], vv = (bn)[3 * (C) + tid];                 \
    float sc = gg / sqrtf(vv + 1e-5f);                                        \
    sbp[(OFF) + tid] = sc;                                                    \
    sbp[(OFF) + (C) + tid] = bb - mm * sc;                                    \
  }

extern "C" __global__ __launch_bounds__(256)
void prep(const float* __restrict__ w1,  const float* __restrict__ bnp1,
          const float* __restrict__ w2,  const float* __restrict__ bnp2,
          const float* __restrict__ wr1, const float* __restrict__ bnr1,
          const float* __restrict__ wr2, const float* __restrict__ bnr2,
          const float* __restrict__ wa1, const float* __restrict__ bna1,
          const float* __restrict__ wb1, const float* __restrict__ bnb1,
          const float* __restrict__ wc1, const float* __restrict__ bnc1,
          const float* __restrict__ wa2, const float* __restrict__ bna2,
          const float* __restrict__ wb2, const float* __restrict__ bnb2,
          const float* __restrict__ wc2, const float* __restrict__ bnc2,
          float* __restrict__ ws)
{
  __shared__ float s_red[4];
  const int tid = threadIdx.x;
  const int b = blockIdx.x;

  if (b == 10) {  // fold all BN params
    float* sbp = ws + WSB;
    GFOLD(bnp1, 5, SB_P1)  GFOLD(bnp2, 10, SB_P2)
    GFOLD(bnr1, 10, SB_R1) GFOLD(bnr2, 10, SB_R2)
    GFOLD(bna1, 70, SB_A1) GFOLD(bnb1, 30, SB_B1) GFOLD(bnc1, 1, SB_C1)
    GFOLD(bna2, 70, SB_A2) GFOLD(bnb2, 30, SB_B2) GFOLD(bnc2, 1, SB_C2)
    return;
  }

  const float* src; int n; int mode; int rofs; float* dst = ws;
  // mode 0: contiguous copy to dst+ofs; mode 1: A-transpose; mode 2: B-transpose
  int ofs = 0;
  switch (b) {
    case 0: src = w1;  ofs = WQ1;      n = 65;   mode = 0; rofs = 0;  break;
    case 1: src = w2;  ofs = WQ2;      n = 450;  mode = 0; rofs = 0;  break;
    case 2: src = wr1; ofs = WR1Q;     n = 100;  mode = 0; rofs = 0;  break;
    case 3: src = wr2; ofs = WR2Q;     n = 100;  mode = 0; rofs = 0;  break;
    case 4: src = wa1; ofs = WQAT;     n = 9800; mode = 1; rofs = 0;  break;
    case 5: src = wb1; ofs = WQBT;     n = 2100; mode = 2; rofs = 0;  break;
    case 6: src = wc1; ofs = WCQ;      n = 30;   mode = 0; rofs = 0;  break;
    case 7: src = wa2; ofs = WQAT;     n = 9800; mode = 1; rofs = 70; break;
    case 8: src = wb2; ofs = WQBT;     n = 2100; mode = 2; rofs = 30; break;
    default:src = wc2; ofs = WCQ + 32; n = 30;   mode = 0; rofs = 0;  break;
  }

  float m = 0.f;
  for (int i = tid; i < n; i += 256) m = fmaxf(m, fabsf(src[i]));
#pragma unroll
  for (int off = 32; off > 0; off >>= 1)
    m = fmaxf(m, __shfl_down(m, off, 64));
  if ((tid & 63) == 0) s_red[tid >> 6] = m;
  __syncthreads();
  m = fmaxf(fmaxf(s_red[0], s_red[1]), fmaxf(s_red[2], s_red[3]));

  float s = m / 127.0f;
  for (int i = tid; i < n; i += 256) {
    float w = src[i];
    float q = rintf(fminf(fmaxf(w / s, -127.f), 127.f)) * s;
    if (mode == 0) {
      dst[ofs + i] = q;
    } else if (mode == 1) {           // A: row r, col c -> [c/4][r] float4
      int r = i / 140 + rofs, c = i % 140;
      dst[ofs + ((c >> 2) * 140 + r) * 4 + (c & 3)] = q;
    } else {                          // B: row r, col c -> [c/2][r] float2
      int r = i / 70 + rofs, c = i % 70;
      dst[ofs + ((c >> 1) * 60 + r) * 2 + (c & 1)] = q;
    }
  }
}

// -------- main pipeline: wave owns 2 elements, ZERO barriers --------------
// Empirical optimum of the family (R5..R14 sweep):
//  - 2 elem/wave (1->52.6us, 2->36.6us, 4->47.5us of kernel time)
//  - small weights LDS-staged (ws[] uniform reads and padded-wide LDS both lost)
//  - A-phase: blocked-transposed global weights, cb-outer (h read once per cb)
//  - unroll caps bound in-flight loads (full unroll -> scratch spill, R3/R4)
extern "C" __global__ __launch_bounds__(TPB, 4)
void taunet(const float* __restrict__ x, const float* __restrict__ ws,
            float* __restrict__ out, int B)
{
  __shared__ __align__(16) float s_h1[EPB * H1S];   // pre1 out; later 140-vec
  __shared__ __align__(16) float s_e[EPB * ES];     // x -> h[140]|t30[60]
  __shared__ __align__(16) float s_small[SMALL_N];

  const int tid = threadIdx.x;
  const int g  = tid >> 5;    // element slot within block (half-wave)
  const int l  = tid & 31;    // lane within element (P1-P4, C)
  const int ln = tid & 63;    // lane within wave
  const int wv = tid >> 6;    // wave within block
  const int gp = 2 * wv;      // wave's first element slot
  const int elem = blockIdx.x * EPB + g;

  // per-wave redundant copy of small weights+BN (identical values -> benign
  // race; each wave's own writes are ordered before its reads => no barrier)
  for (int i = ln; i < SMALL_N; i += 64) s_small[i] = ws[i];

  // stage x: wave stages its own two elements (coalesced float4)
  {
    const float4* xb = (const float4*)x;
#pragma unroll
    for (int it = 0; it < 2; ++it) {
      int e = gp + it;
      int ge = blockIdx.x * EPB + e;
      if (ge < B) {
        float4 v = xb[ge * 64 + ln];
        *(float4*)&s_e[e * ES + ln * 4] = v;
      }
    }
  }

  const float* sb = &s_small[WSB];

  // ---- P1: pre1 (Cin=1, K=13, stride 5) -> h1[5][49] ----
  // weights + BN wave-uniform from ws[] -> scalar s_loads (SMEM pipe)
  {
    const float* xe = &s_e[g * ES];
#pragma unroll
    for (int rep = 0; rep < 2; ++rep) {
      int p = l + 32 * rep;
      bool act = p < 49;
      int ps = act ? p : 0;
      float win[13];
#pragma unroll
      for (int k = 0; k < 13; ++k) win[k] = xe[5 * ps + k];
#pragma unroll
      for (int ci = 0; ci < 5; ++ci) {
        float a0 = 0.f, a1 = 0.f;
#pragma unroll
        for (int k = 0; k < 13; ++k) {
          float d = fabsf(win[k] - ws[WQ1 + ci * 13 + k]);
          if (k & 1) a1 += d; else a0 += d;
        }
        float v = fmaxf(fmaf(-(a0 + a1), ws[WSB + SB_P1 + ci],
                             ws[WSB + SB_P1 + 5 + ci]), 0.f);
        if (act) s_h1[g * H1S + ci * 49 + ps] = v;
      }
    }
  }

  // ---- P2: pre2 (Cin=5, K=9, stride 3) -> h2[10][14] ----
  // half-wave: lane = ow(14 of 16) x co-half(2); ci-outer, 9-reg window
  {
    const int ch = l >> 4;
    const int ow16 = l & 15;
    const bool act = ow16 < 14;
    const int ow = act ? ow16 : 0;
    const float* h1b = &s_h1[g * H1S];
    float acc[5] = {0.f, 0.f, 0.f, 0.f, 0.f};
#pragma unroll
    for (int ci = 0; ci < 5; ++ci) {
      float w9[9];
#pragma unroll
      for (int k = 0; k < 9; ++k) w9[k] = h1b[ci * 49 + 3 * ow + k];
#pragma unroll
      for (int c = 0; c < 5; ++c) {
        int co = ch * 5 + c;
        float s0 = 0.f, s1 = 0.f;
#pragma unroll
        for (int k = 0; k < 9; ++k) {
          float d = fabsf(w9[k] - s_small[WQ2 + co * 45 + ci * 9 + k]);
          if (k & 1) s1 += d; else s0 += d;
        }
        acc[c] += s0 + s1;
      }
    }
#pragma unroll
    for (int c = 0; c < 5; ++c) {
      int co = ch * 5 + c;
      float v = fmaxf(fmaf(-acc[c], sb[SB_P2 + co], sb[SB_P2 + 10 + co]), 0.f);
      if (act) s_e[g * ES + co * 14 + ow] = v;
    }
  }

  // ---- P3: r1 (10x10, K=1) + relu -> t1 ----
#pragma unroll
  for (int j = 0; j < 5; ++j) {
    int idx = l + 32 * j;
    if (idx < 140) {
      int co = idx / 14, ow = idx % 14;
      float a0 = 0.f, a1 = 0.f;
#pragma unroll
      for (int ci = 0; ci < 10; ++ci) {
        float d = fabsf(s_e[g * ES + ci * 14 + ow] - s_small[WR1Q + co * 10 + ci]);
        if (ci & 1) a1 += d; else a0 += d;
      }
      s_e[g * ES + 140 + idx] =
          fmaxf(fmaf(-(a0 + a1), sb[SB_R1 + co], sb[SB_R1 + 10 + co]), 0.f);
    }
  }

  // ---- P4: r2 (no relu) + residual, h = relu(t2 + h2), in place ----
#pragma unroll
  for (int j = 0; j < 5; ++j) {
    int idx = l + 32 * j;
    if (idx < 140) {
      int co = idx / 14, ow = idx % 14;
      float a0 = 0.f, a1 = 0.f;
#pragma unroll
      for (int ci = 0; ci < 10; ++ci) {
        float d = fabsf(s_e[g * ES + 140 + ci * 14 + ow] - s_small[WR2Q + co * 10 + ci]);
        if (ci & 1) a1 += d; else a0 += d;
      }
      float t2 = fmaf(-(a0 + a1), sb[SB_R2 + co], sb[SB_R2 + 10 + co]);
      s_e[g * ES + idx] = fmaxf(t2 + s_e[g * ES + idx], 0.f);
    }
  }

  // ---- A/B fused branches, wave-wide ----
  {
    const float* hb0 = &s_e[gp * ES];         // element e0 = gp
    const float* hb1 = &s_e[(gp + 1) * ES];   // element e1 = gp+1

    // A: cb-outer; h4/k4 LDS-read ONCE per cb (70 b128/wave vs 210);
    // 3 row-sets accumulate in 24 regs. unroll 2 (spill discipline).
    const int r2 = (ln + 128 > 139) ? 139 : ln + 128;
    const int rows[3] = {ln, ln + 64, r2};
    float accA[3][4], accB[3][4];
#pragma unroll
    for (int p = 0; p < 3; ++p)
#pragma unroll
      for (int j = 0; j < 4; ++j) { accA[p][j] = 0.f; accB[p][j] = 0.f; }
#pragma unroll 2
    for (int cb = 0; cb < 35; ++cb) {
      float4 h4 = *(const float4*)&hb0[cb * 4];
      float4 k4 = *(const float4*)&hb1[cb * 4];
#pragma unroll
      for (int p = 0; p < 3; ++p) {
        float4 w4 = *(const float4*)&ws[WQAT + (cb * 140 + rows[p]) * 4];
        accA[p][0] += fabsf(h4.x - w4.x);
        accA[p][1] += fabsf(h4.y - w4.y);
        accA[p][2] += fabsf(h4.z - w4.z);
        accA[p][3] += fabsf(h4.w - w4.w);
        accB[p][0] += fabsf(k4.x - w4.x);
        accB[p][1] += fabsf(k4.y - w4.y);
        accB[p][2] += fabsf(k4.z - w4.z);
        accB[p][3] += fabsf(k4.w - w4.w);
      }
    }
#pragma unroll
    for (int p = 0; p < 3; ++p) {
      int cl = rows[p];
      bool act = (p < 2) || (ln < 12);
      if (act) {
        int co  = cl < 70 ? cl : cl - 70;
        int off = cl < 70 ? SB_A1 : SB_A2;
        float sc = sb[off + co], bi = sb[off + 70 + co];
        float sadA = (accA[p][0] + accA[p][1]) + (accA[p][2] + accA[p][3]);
        float sadB = (accB[p][0] + accB[p][1]) + (accB[p][2] + accB[p][3]);
        s_h1[gp * H1S + cl]       = fmaxf(fmaf(-sadA, sc, bi), 0.f);
        s_h1[(gp + 1) * H1S + cl] = fmaxf(fmaf(-sadB, sc, bi), 0.f);
      }
    }

    // B: 60 fused rows in one pass; dense float2 weight loads
    {
      bool act = ln < 60;
      int rl = act ? ln : 0;
      int br = rl >= 30;
      int co = br ? rl - 30 : rl;
      const float* h0 = &s_h1[gp * H1S + br * 70];
      const float* h1 = &s_h1[(gp + 1) * H1S + br * 70];
      int off = br ? SB_B2 : SB_B1;
      float a0 = 0.f, a1 = 0.f, b0 = 0.f, b1 = 0.f;
#pragma unroll 8
      for (int ci = 0; ci < 35; ++ci) {
        float2 w2v = *(const float2*)&ws[WQBT + (ci * 60 + rl) * 2];
        a0 += fabsf(h0[2 * ci]     - w2v.x);
        a1 += fabsf(h0[2 * ci + 1] - w2v.y);
        b0 += fabsf(h1[2 * ci]     - w2v.x);
        b1 += fabsf(h1[2 * ci + 1] - w2v.y);
      }
      if (act) {
        float sc = sb[off + co], bi = sb[off + 30 + co];
        s_e[gp * ES + 140 + rl]       = fmaxf(fmaf(-(a0 + a1), sc, bi), 0.f);
        s_e[(gp + 1) * ES + 140 + rl] = fmaxf(fmaf(-(b0 + b1), sc, bi), 0.f);
      }
    }

    // C: per element (half-wave), both branches sequentially; width-32 tree
    for (int br = 0; br < 2; ++br) {
      float d = 0.f;
      if (l < 30)
        d = fabsf(s_e[g * ES + 140 + br * 30 + l] - s_small[WCQ + br * 32 + l]);
#pragma unroll
      for (int off = 16; off > 0; off >>= 1)
        d += __shfl_down(d, off, 32);
      if (l == 0 && elem < B) {
        int sbC = br ? SB_C2 : SB_C1;
        out[br * B + elem] = fmaxf(fmaf(-d, sb[sbC], sb[sbC + 1]), 0.f);
      }
    }
  }
}

extern "C" void kernel_launch(void* const* d_in, const int* in_sizes, int n_in,
                              void* d_out, int out_size, void* d_ws, size_t ws_size,
                              hipStream_t stream) {
  const float* x    = (const float*)d_in[0];
  const float* w1   = (const float*)d_in[1];
  const float* bnp1 = (const float*)d_in[2];
  const float* w2   = (const float*)d_in[3];
  const float* bnp2 = (const float*)d_in[4];
  const float* wr1  = (const float*)d_in[5];
  const float* bnr1 = (const float*)d_in[6];
  const float* wr2  = (const float*)d_in[7];
  const float* bnr2 = (const float*)d_in[8];
  const float* wa1  = (const float*)d_in[9];
  const float* bna1 = (const float*)d_in[10];
  const float* wb1  = (const float*)d_in[11];
  const float* bnb1 = (const float*)d_in[12];
  const float* wc1  = (const float*)d_in[13];
  const float* bnc1 = (const float*)d_in[14];
  const float* wa2  = (const float*)d_in[15];
  const float* bna2 = (const float*)d_in[16];
  const float* wb2  = (const float*)d_in[17];
  const float* bnb2 = (const float*)d_in[18];
  const float* wc2  = (const float*)d_in[19];
  const float* bnc2 = (const float*)d_in[20];

  float* ws = (float*)d_ws;
  int B = in_sizes[0] / 256;
  int blocks = (B + EPB - 1) / EPB;

  hipLaunchKernelGGL(prep, dim3(11), dim3(256), 0, stream,
                     w1, bnp1, w2, bnp2, wr1, bnr1, wr2, bnr2,
                     wa1, bna1, wb1, bnb1, wc1, bnc1,
                     wa2, bna2, wb2, bnb2, wc2, bnc2, ws);

  hipLaunchKernelGGL(taunet, dim3(blocks), dim3(TPB), 0, stream,
                     x, ws, (float*)d_out, B);
}